// Round 2
// baseline (1241.616 us; speedup 1.0000x reference)
//
#include <hip/hip_runtime.h>
#include <hip/hip_bf16.h>
#include <stdint.h>

// ---------- helpers ----------
__device__ __forceinline__ float tf(float v) { return v; }
__device__ __forceinline__ float tf(__hip_bfloat16 v) { return __bfloat162float(v); }

typedef __attribute__((ext_vector_type(8))) short bf16x8;
typedef __attribute__((ext_vector_type(4))) float f32x4;

#define GLD_LDS16(gp, lp)                                                        \
  __builtin_amdgcn_global_load_lds((const __attribute__((address_space(1))) void*)(gp), \
                                   (__attribute__((address_space(3))) void*)(lp), 16, 0, 0)

// ---------- pack W into MFMA A-fragment order ----------
// frag fid = mb*48 + kb (mb = o>>4, kb = r>>5); lane l holds o = mb*16+(l&15),
// k-octet elements r = kb*32 + (l>>4)*8 + j. out[fid*512 + l*8 + j] = bf16(w[o*1536+r]).
__global__ __launch_bounds__(256) void pack_w_kernel(const float* __restrict__ w,
                                                     __hip_bfloat16* __restrict__ d) {
  int i = blockIdx.x * 256 + threadIdx.x;  // 0 .. 786431
  int fid = i >> 9;
  int within = i & 511;
  int lane = within >> 3;
  int j = within & 7;
  int mb = fid / 48;
  int kb = fid - mb * 48;
  int o = mb * 16 + (lane & 15);
  int r = kb * 32 + (lane >> 4) * 8 + j;
  d[i] = __float2bfloat16(w[o * 1536 + r]);
}

__global__ __launch_bounds__(256) void mask_out_kernel(const float* __restrict__ m,
                                                       float* __restrict__ o, int n) {
  int i = blockIdx.x * 256 + threadIdx.x;
  if (i < n) o[i] = (m[i] != 0.f) ? 1.f : 0.f;
}

// ---------- offset conv: off_out[b,k,t] = ob[k] + off_in[b,k,t] + sum_{c,j} ow[k,c,j]*x[b,c,t+j-1]
template <typename XT>
__global__ __launch_bounds__(256) void offconv_kernel(const XT* __restrict__ x,
                                                      const float* __restrict__ ow,
                                                      const float* __restrict__ ob,
                                                      const float* __restrict__ offin,
                                                      float* __restrict__ offout, int T) {
  __shared__ float sw[4608];
  __shared__ float red[3][4][64];
  int tid = threadIdx.x;
  for (int i = tid; i < 4608; i += 256) sw[i] = ow[i];
  __syncthreads();
  int lane = tid & 63, g = tid >> 6;
  int nchunk = T >> 6;
  int b = blockIdx.x / nchunk;
  int t = ((blockIdx.x % nchunk) << 6) + lane;
  const XT* xb = x + ((size_t)b * 512 + (size_t)g * 128) * T;
  float a0 = 0.f, a1 = 0.f, a2 = 0.f;
  for (int c = 0; c < 128; ++c) {
    const XT* xr = xb + (size_t)c * T;
    float xm = (t > 0) ? tf(xr[t - 1]) : 0.f;
    float x0 = tf(xr[t]);
    float xp = (t < T - 1) ? tf(xr[t + 1]) : 0.f;
    const float* wp = sw + (g * 128 + c) * 3;
    a0 += wp[0] * xm + wp[1] * x0 + wp[2] * xp;
    a1 += wp[1536] * xm + wp[1537] * x0 + wp[1538] * xp;
    a2 += wp[3072] * xm + wp[3073] * x0 + wp[3074] * xp;
  }
  red[0][g][lane] = a0;
  red[1][g][lane] = a1;
  red[2][g][lane] = a2;
  __syncthreads();
  if (g == 0) {
    for (int k = 0; k < 3; ++k) {
      float s = red[k][0][lane] + red[k][1][lane] + red[k][2][lane] + red[k][3][lane];
      int oi = (b * 3 + k) * T + t;
      offout[oi] = s + ob[k] + offin[oi];
    }
  }
}

// ---------- sampling, fragment-order output ----------
// One wave per 16-row n-strip (ntile). Lane l: n = ntile*16+(l&15), r-octet = l>>4.
// Iterates kb = 0..47, writing one full 1KB B-fragment per wave per kb
// at S[(ntile*48+kb)*512 + l*8 .. +8] — fully coalesced 16B/lane stores.
// Gather loads: 16 consecutive-t lanes read a clustered window of one x row.
template <typename XT>
__global__ __launch_bounds__(256) void sample_kernel(const XT* __restrict__ x,
                                                     const float* __restrict__ off,
                                                     __hip_bfloat16* __restrict__ S, int T,
                                                     int tsh) {
  int tid = threadIdx.x;
  int lane = tid & 63, wid = tid >> 6;
  int ntile = blockIdx.x * 4 + wid;
  int n = (ntile << 4) + (lane & 15);
  int b = n >> tsh;
  int t = n & (T - 1);
  int ro = lane >> 4;

  int p0[3];
  float fr[3];
#pragma unroll
  for (int k = 0; k < 3; ++k) {
    float o = off[((b * 3 + k) << tsh) + t];
    float pos = (float)(t + k - 1) + o;
    float p0f = floorf(pos);
    fr[k] = pos - p0f;
    p0[k] = (int)p0f;
  }
  const XT* xb = x + ((size_t)b << (9 + tsh));
  short* Sp = (short*)S;

  for (int kb = 0; kb < 48; ++kb) {
    int r0 = kb * 32 + ro * 8;
    int c = r0 / 3;
    int k = r0 - c * 3;
    bf16x8 ov;
#pragma unroll
    for (int j = 0; j < 8; ++j) {
      const XT* xr = xb + ((size_t)c << tsh);
      int q0 = p0[k], q1 = q0 + 1;
      float f = fr[k];
      float v0 = ((unsigned)q0 < (unsigned)T) ? tf(xr[q0]) : 0.f;
      float v1 = ((unsigned)q1 < (unsigned)T) ? tf(xr[q1]) : 0.f;
      __hip_bfloat16 hv = __float2bfloat16(v0 * (1.f - f) + v1 * f);
      ov[j] = *reinterpret_cast<short*>(&hv);
      if (++k == 3) { k = 0; ++c; }
    }
    *(bf16x8*)(Sp + (((size_t)(ntile * 48 + kb)) << 9) + lane * 8) = ov;
  }
}

// ---------- GEMM: C[o][n] = sum_r W[o][r]*S[n][r]; both operands fragment-packed.
// 128x128 tile, BK=64, 4 waves (2x2), mfma_f32_16x16x32_bf16. Staging is pure
// contiguous 1KB fragment loads via global_load_lds (lane*16B).
template <bool OUT_BF16>
__global__ __launch_bounds__(256) void gemm_kernel(const __hip_bfloat16* __restrict__ Wf,
                                                   const __hip_bfloat16* __restrict__ Sf,
                                                   const float* __restrict__ bias,
                                                   const float* __restrict__ mask,
                                                   void* __restrict__ outp, int T, int tsh) {
  __shared__ short lds[16384];  // 32 fragments x 512 elems
  int tid = threadIdx.x;
  int lane = tid & 63;
  int wid = tid >> 6;
  int lrow = lane & 15, lq = lane >> 4;
  int mq = wid & 1, nq = wid >> 1;
  int mbase = blockIdx.x << 3;  // m-subtile base (16-row units)
  int nbase = blockIdx.y << 3;
  int m0 = blockIdx.x << 7;
  int n0 = blockIdx.y << 7;

  f32x4 acc[4][4] = {};

  const short* wg = (const short*)Wf + lane * 8;
  const short* sg = (const short*)Sf + lane * 8;

  for (int kt = 0; kt < 24; ++kt) {
    __syncthreads();
#pragma unroll
    for (int i = 0; i < 8; ++i) {
      int f = wid * 8 + i;  // 0..15 W frags (mt*2+kc), 16..31 S frags
      int kc = f & 1;
      int mt = (f >> 1) & 7;
      int fid = ((f < 16 ? mbase : nbase) + mt) * 48 + (kt << 1) + kc;
      const short* g = (f < 16 ? wg : sg) + ((size_t)fid << 9);
      GLD_LDS16(g, &lds[f * 512]);
    }
    __syncthreads();
#pragma unroll
    for (int kc = 0; kc < 2; ++kc) {
      bf16x8 av[4], bvv[4];
#pragma unroll
      for (int i = 0; i < 4; ++i)
        av[i] = *(const bf16x8*)&lds[((mq * 4 + i) * 2 + kc) * 512 + lane * 8];
#pragma unroll
      for (int j = 0; j < 4; ++j)
        bvv[j] = *(const bf16x8*)&lds[8192 + ((nq * 4 + j) * 2 + kc) * 512 + lane * 8];
#pragma unroll
      for (int i = 0; i < 4; ++i)
#pragma unroll
        for (int j = 0; j < 4; ++j)
          acc[i][j] = __builtin_amdgcn_mfma_f32_16x16x32_bf16(av[i], bvv[j], acc[i][j], 0, 0, 0);
    }
  }

  // epilogue: D row = (lane>>4)*4 + reg, col = lane&15
  int bb = n0 >> tsh;
  int tb = n0 & (T - 1);
  float bvals[4][4];
#pragma unroll
  for (int i = 0; i < 4; ++i)
#pragma unroll
    for (int r = 0; r < 4; ++r) bvals[i][r] = bias[m0 + mq * 64 + i * 16 + lq * 4 + r];
#pragma unroll
  for (int j = 0; j < 4; ++j) {
    int col = nq * 64 + j * 16 + lrow;
    int t = tb + col;
    float mk = mask[(bb << tsh) + t];
#pragma unroll
    for (int i = 0; i < 4; ++i) {
      int row = mq * 64 + i * 16 + lq * 4;
#pragma unroll
      for (int r = 0; r < 4; ++r) {
        float v = acc[i][j][r] + bvals[i][r];
        v = fmaxf(v, 0.f) * mk;
        size_t oi = ((((size_t)bb << 9) + (size_t)(m0 + row + r)) << tsh) + t;
        if (OUT_BF16)
          ((__hip_bfloat16*)outp)[oi] = __float2bfloat16(v);
        else
          ((float*)outp)[oi] = v;
      }
    }
  }
}

// ---------- launch ----------
extern "C" void kernel_launch(void* const* d_in, const int* in_sizes, int n_in, void* d_out,
                              int out_size, void* d_ws, size_t ws_size, hipStream_t stream) {
  const float* feats[3] = {(const float*)d_in[0], (const float*)d_in[3], (const float*)d_in[6]};
  const float* maskp[3] = {(const float*)d_in[1], (const float*)d_in[4], (const float*)d_in[7]};
  const float* offs[3] = {(const float*)d_in[2], (const float*)d_in[5], (const float*)d_in[8]};
  const float* w[2] = {(const float*)d_in[9], (const float*)d_in[13]};
  const float* bias[2] = {(const float*)d_in[10], (const float*)d_in[14]};
  const float* ow[2] = {(const float*)d_in[11], (const float*)d_in[15]};
  const float* ob[2] = {(const float*)d_in[12], (const float*)d_in[16]};

  const int Ts[3] = {2048, 1024, 512};
  const size_t YOFF[3] = {0, 8388608, 12582912};
  const size_t MOFF[3] = {14680064, 14696448, 14704640};

  uint8_t* ws = (uint8_t*)d_ws;
  __hip_bfloat16* Wf[2] = {(__hip_bfloat16*)ws, (__hip_bfloat16*)(ws + 1572864)};
  float* offbuf = (float*)(ws + 3145728);                 // 196,608 B
  __hip_bfloat16* x1 = (__hip_bfloat16*)(ws + 3342336);   // 16,777,216 B
  __hip_bfloat16* Sm = (__hip_bfloat16*)(ws + 20119552);  // 50,331,648 B

  for (int l = 0; l < 2; ++l)
    pack_w_kernel<<<786432 / 256, 256, 0, stream>>>(w[l], Wf[l]);

  float* outf = (float*)d_out;
  for (int lv = 0; lv < 3; ++lv) {
    int T = Ts[lv];
    int tsh = 11 - lv;
    int N = 8 * T;

    mask_out_kernel<<<(8 * T + 255) / 256, 256, 0, stream>>>(maskp[lv], outf + MOFF[lv], 8 * T);

    // layer 1 (x = feats, fp32)
    offconv_kernel<float><<<8 * (T >> 6), 256, 0, stream>>>(feats[lv], ow[0], ob[0], offs[lv],
                                                            offbuf, T);
    sample_kernel<float><<<N >> 6, 256, 0, stream>>>(feats[lv], offbuf, Sm, T, tsh);
    gemm_kernel<true><<<dim3(4, N >> 7), 256, 0, stream>>>(Wf[0], Sm, bias[0], maskp[lv],
                                                           (void*)x1, T, tsh);

    // layer 2 (x = x1, bf16)
    offconv_kernel<__hip_bfloat16><<<8 * (T >> 6), 256, 0, stream>>>(x1, ow[1], ob[1], offbuf,
                                                                     offbuf, T);
    sample_kernel<__hip_bfloat16><<<N >> 6, 256, 0, stream>>>(x1, offbuf, Sm, T, tsh);
    gemm_kernel<false><<<dim3(4, N >> 7), 256, 0, stream>>>(Wf[1], Sm, bias[1], maskp[lv],
                                                            (void*)(outf + YOFF[lv]), T, tsh);
  }
}

// Round 3
// 623.979 us; speedup vs baseline: 1.9898x; 1.9898x over previous
//
#include <hip/hip_runtime.h>
#include <hip/hip_bf16.h>
#include <stdint.h>

// ---------- helpers ----------
__device__ __forceinline__ float tf(float v) { return v; }
__device__ __forceinline__ float tf(__hip_bfloat16 v) { return __bfloat162float(v); }

typedef __attribute__((ext_vector_type(8))) short bf16x8;
typedef __attribute__((ext_vector_type(4))) float f32x4;

#define GLD_LDS16(gp, lp)                                                        \
  __builtin_amdgcn_global_load_lds((const __attribute__((address_space(1))) void*)(gp), \
                                   (__attribute__((address_space(3))) void*)(lp), 16, 0, 0)

// ---------- pack W into MFMA A-fragment order ----------
__global__ __launch_bounds__(256) void pack_w_kernel(const float* __restrict__ w,
                                                     __hip_bfloat16* __restrict__ d) {
  int i = blockIdx.x * 256 + threadIdx.x;  // 0 .. 786431
  int fid = i >> 9;
  int within = i & 511;
  int lane = within >> 3;
  int j = within & 7;
  int mb = fid / 48;
  int kb = fid - mb * 48;
  int o = mb * 16 + (lane & 15);
  int r = kb * 32 + (lane >> 4) * 8 + j;
  d[i] = __float2bfloat16(w[o * 1536 + r]);
}

__global__ __launch_bounds__(256) void mask_out_kernel(const float* __restrict__ m,
                                                       float* __restrict__ o, int n) {
  int i = blockIdx.x * 256 + threadIdx.x;
  if (i < n) o[i] = (m[i] != 0.f) ? 1.f : 0.f;
}

// ---------- offset conv, split across 4 channel-groups with atomic accumulate ----------
// offinit: offout[b,k,t] = offin[b,k,t] + ob[k]
__global__ __launch_bounds__(256) void offinit_kernel(const float* __restrict__ offin,
                                                      const float* __restrict__ ob,
                                                      float* __restrict__ offout, int tsh, int n) {
  int i = blockIdx.x * 256 + threadIdx.x;
  if (i >= n) return;
  int k = (i >> tsh) % 3;
  offout[i] = offin[i] + ob[k];
}

// grid (B*T/64, 4cg); block 256 = 4 waves x 64 t-lanes; wave w covers 32 channels.
template <typename XT>
__global__ __launch_bounds__(256) void offconv_kernel(const XT* __restrict__ x,
                                                      const float* __restrict__ ow,
                                                      float* __restrict__ offout, int T) {
  __shared__ float red[3][4][64];
  int tid = threadIdx.x;
  int lane = tid & 63, w = tid >> 6;
  int nchunk = T >> 6;
  int bx = blockIdx.x;
  int b = bx / nchunk;
  int tb = (bx % nchunk) << 6;
  int t = tb + lane;
  int c0 = blockIdx.y * 128 + w * 32;
  const XT* xb = x + ((size_t)b * 512 + c0) * T;
  float a0 = 0.f, a1 = 0.f, a2 = 0.f;
  for (int c = 0; c < 32; ++c) {
    const XT* xr = xb + (size_t)c * T;
    float xm = (t > 0) ? tf(xr[t - 1]) : 0.f;
    float x0 = tf(xr[t]);
    float xp = (t < T - 1) ? tf(xr[t + 1]) : 0.f;
    const float* wp = ow + (c0 + c) * 3;
    a0 += wp[0] * xm + wp[1] * x0 + wp[2] * xp;
    a1 += wp[1536] * xm + wp[1537] * x0 + wp[1538] * xp;
    a2 += wp[3072] * xm + wp[3073] * x0 + wp[3074] * xp;
  }
  red[0][w][lane] = a0;
  red[1][w][lane] = a1;
  red[2][w][lane] = a2;
  __syncthreads();
  if (w < 3) {  // wave w handles output channel k=w
    float s = red[w][0][lane] + red[w][1][lane] + red[w][2][lane] + red[w][3][lane];
    atomicAdd(&offout[(b * 3 + w) * T + tb + lane], s);
  }
}

// ---------- sampling, fragment-order output, kb split across gridDim.y ----------
// Wave handles ntile (16 n-rows) x 8 kb fragments. Lane l: n = ntile*16+(l&15),
// r-octet = l>>4. Stores one contiguous 1KB B-fragment per kb (16B/lane).
template <typename XT>
__global__ __launch_bounds__(256) void sample_kernel(const XT* __restrict__ x,
                                                     const float* __restrict__ off,
                                                     __hip_bfloat16* __restrict__ S, int T,
                                                     int tsh) {
  int tid = threadIdx.x;
  int lane = tid & 63, wid = tid >> 6;
  int ntile = blockIdx.x * 4 + wid;
  int kb0 = blockIdx.y << 3;
  int n = (ntile << 4) + (lane & 15);
  int b = n >> tsh;
  int t = n & (T - 1);
  int ro = lane >> 4;

  int p0[3];
  float fr[3];
#pragma unroll
  for (int k = 0; k < 3; ++k) {
    float o = off[((b * 3 + k) << tsh) + t];
    float pos = (float)(t + k - 1) + o;
    float p0f = floorf(pos);
    fr[k] = pos - p0f;
    p0[k] = (int)p0f;
  }
  const XT* xb = x + ((size_t)b << (9 + tsh));
  short* Sp = (short*)S;

  for (int kb = kb0; kb < kb0 + 8; ++kb) {
    int r0 = kb * 32 + ro * 8;
    int c = r0 / 3;
    int k = r0 - c * 3;
    bf16x8 ov;
#pragma unroll
    for (int j = 0; j < 8; ++j) {
      const XT* xr = xb + ((size_t)c << tsh);
      int q0 = p0[k], q1 = q0 + 1;
      float f = fr[k];
      float v0 = ((unsigned)q0 < (unsigned)T) ? tf(xr[q0]) : 0.f;
      float v1 = ((unsigned)q1 < (unsigned)T) ? tf(xr[q1]) : 0.f;
      __hip_bfloat16 hv = __float2bfloat16(v0 * (1.f - f) + v1 * f);
      ov[j] = *reinterpret_cast<short*>(&hv);
      if (++k == 3) { k = 0; ++c; }
    }
    *(bf16x8*)(Sp + (((size_t)(ntile * 48 + kb)) << 9) + lane * 8) = ov;
  }
}

// ---------- GEMM: C[o][n] = sum_r W[o][r]*S[n][r]; both operands fragment-packed.
template <bool OUT_BF16>
__global__ __launch_bounds__(256) void gemm_kernel(const __hip_bfloat16* __restrict__ Wf,
                                                   const __hip_bfloat16* __restrict__ Sf,
                                                   const float* __restrict__ bias,
                                                   const float* __restrict__ mask,
                                                   void* __restrict__ outp, int T, int tsh) {
  __shared__ short lds[16384];  // 32 fragments x 512 elems
  int tid = threadIdx.x;
  int lane = tid & 63;
  int wid = tid >> 6;
  int lrow = lane & 15, lq = lane >> 4;
  int mq = wid & 1, nq = wid >> 1;
  int mbase = blockIdx.x << 3;
  int nbase = blockIdx.y << 3;
  int m0 = blockIdx.x << 7;
  int n0 = blockIdx.y << 7;

  f32x4 acc[4][4] = {};

  const short* wg = (const short*)Wf + lane * 8;
  const short* sg = (const short*)Sf + lane * 8;

  for (int kt = 0; kt < 24; ++kt) {
    __syncthreads();
#pragma unroll
    for (int i = 0; i < 8; ++i) {
      int f = wid * 8 + i;  // 0..15 W frags (mt*2+kc), 16..31 S frags
      int kc = f & 1;
      int mt = (f >> 1) & 7;
      int fid = ((f < 16 ? mbase : nbase) + mt) * 48 + (kt << 1) + kc;
      const short* g = (f < 16 ? wg : sg) + ((size_t)fid << 9);
      GLD_LDS16(g, &lds[f * 512]);
    }
    __syncthreads();
#pragma unroll
    for (int kc = 0; kc < 2; ++kc) {
      bf16x8 av[4], bvv[4];
#pragma unroll
      for (int i = 0; i < 4; ++i)
        av[i] = *(const bf16x8*)&lds[((mq * 4 + i) * 2 + kc) * 512 + lane * 8];
#pragma unroll
      for (int j = 0; j < 4; ++j)
        bvv[j] = *(const bf16x8*)&lds[8192 + ((nq * 4 + j) * 2 + kc) * 512 + lane * 8];
#pragma unroll
      for (int i = 0; i < 4; ++i)
#pragma unroll
        for (int j = 0; j < 4; ++j)
          acc[i][j] = __builtin_amdgcn_mfma_f32_16x16x32_bf16(av[i], bvv[j], acc[i][j], 0, 0, 0);
    }
  }

  // epilogue: D row = (lane>>4)*4 + reg, col = lane&15
  int bb = n0 >> tsh;
  int tb = n0 & (T - 1);
  float bvals[4][4];
#pragma unroll
  for (int i = 0; i < 4; ++i)
#pragma unroll
    for (int r = 0; r < 4; ++r) bvals[i][r] = bias[m0 + mq * 64 + i * 16 + lq * 4 + r];
#pragma unroll
  for (int j = 0; j < 4; ++j) {
    int col = nq * 64 + j * 16 + lrow;
    int t = tb + col;
    float mk = mask[(bb << tsh) + t];
#pragma unroll
    for (int i = 0; i < 4; ++i) {
      int row = mq * 64 + i * 16 + lq * 4;
#pragma unroll
      for (int r = 0; r < 4; ++r) {
        float v = acc[i][j][r] + bvals[i][r];
        v = fmaxf(v, 0.f) * mk;
        size_t oi = ((((size_t)bb << 9) + (size_t)(m0 + row + r)) << tsh) + t;
        if (OUT_BF16)
          ((__hip_bfloat16*)outp)[oi] = __float2bfloat16(v);
        else
          ((float*)outp)[oi] = v;
      }
    }
  }
}

// ---------- launch ----------
extern "C" void kernel_launch(void* const* d_in, const int* in_sizes, int n_in, void* d_out,
                              int out_size, void* d_ws, size_t ws_size, hipStream_t stream) {
  const float* feats[3] = {(const float*)d_in[0], (const float*)d_in[3], (const float*)d_in[6]};
  const float* maskp[3] = {(const float*)d_in[1], (const float*)d_in[4], (const float*)d_in[7]};
  const float* offs[3] = {(const float*)d_in[2], (const float*)d_in[5], (const float*)d_in[8]};
  const float* w[2] = {(const float*)d_in[9], (const float*)d_in[13]};
  const float* bias[2] = {(const float*)d_in[10], (const float*)d_in[14]};
  const float* ow[2] = {(const float*)d_in[11], (const float*)d_in[15]};
  const float* ob[2] = {(const float*)d_in[12], (const float*)d_in[16]};

  const int Ts[3] = {2048, 1024, 512};
  const size_t YOFF[3] = {0, 8388608, 12582912};
  const size_t MOFF[3] = {14680064, 14696448, 14704640};

  uint8_t* ws = (uint8_t*)d_ws;
  __hip_bfloat16* Wf[2] = {(__hip_bfloat16*)ws, (__hip_bfloat16*)(ws + 1572864)};
  float* offbuf = (float*)(ws + 3145728);                 // 196,608 B
  __hip_bfloat16* x1 = (__hip_bfloat16*)(ws + 3342336);   // 16,777,216 B
  __hip_bfloat16* Sm = (__hip_bfloat16*)(ws + 20119552);  // 50,331,648 B

  for (int l = 0; l < 2; ++l)
    pack_w_kernel<<<786432 / 256, 256, 0, stream>>>(w[l], Wf[l]);

  float* outf = (float*)d_out;
  for (int lv = 0; lv < 3; ++lv) {
    int T = Ts[lv];
    int tsh = 11 - lv;
    int N = 8 * T;
    int noff = 8 * 3 * T;

    mask_out_kernel<<<(8 * T + 255) / 256, 256, 0, stream>>>(maskp[lv], outf + MOFF[lv], 8 * T);

    // layer 1 (x = feats, fp32)
    offinit_kernel<<<(noff + 255) / 256, 256, 0, stream>>>(offs[lv], ob[0], offbuf, tsh, noff);
    offconv_kernel<float><<<dim3(8 * (T >> 6), 4), 256, 0, stream>>>(feats[lv], ow[0], offbuf, T);
    sample_kernel<float><<<dim3(N >> 6, 6), 256, 0, stream>>>(feats[lv], offbuf, Sm, T, tsh);
    gemm_kernel<true><<<dim3(4, N >> 7), 256, 0, stream>>>(Wf[0], Sm, bias[0], maskp[lv],
                                                           (void*)x1, T, tsh);

    // layer 2 (x = x1, bf16)
    offinit_kernel<<<(noff + 255) / 256, 256, 0, stream>>>(offbuf, ob[1], offbuf, tsh, noff);
    offconv_kernel<__hip_bfloat16><<<dim3(8 * (T >> 6), 4), 256, 0, stream>>>(x1, ow[1], offbuf, T);
    sample_kernel<__hip_bfloat16><<<dim3(N >> 6, 6), 256, 0, stream>>>(x1, offbuf, Sm, T, tsh);
    gemm_kernel<false><<<dim3(4, N >> 7), 256, 0, stream>>>(Wf[1], Sm, bias[1], maskp[lv],
                                                            (void*)(outf + YOFF[lv]), T, tsh);
  }
}

// Round 4
// 568.024 us; speedup vs baseline: 2.1859x; 1.0985x over previous
//
#include <hip/hip_runtime.h>
#include <hip/hip_bf16.h>
#include <stdint.h>

// ---------- helpers ----------
__device__ __forceinline__ float tf(float v) { return v; }
__device__ __forceinline__ float tf(__hip_bfloat16 v) { return __bfloat162float(v); }

typedef __attribute__((ext_vector_type(8))) short bf16x8;
typedef __attribute__((ext_vector_type(4))) float f32x4;

#define GLD_LDS16(gp, lp)                                                        \
  __builtin_amdgcn_global_load_lds((const __attribute__((address_space(1))) void*)(gp), \
                                   (__attribute__((address_space(3))) void*)(lp), 16, 0, 0)

// K-permutation: r = k*512 + c (k-major). W packed with same map; GEMM invariant.

// ---------- pack both W into MFMA A-fragment order, k-major ----------
__global__ __launch_bounds__(256) void pack_w_kernel(const float* __restrict__ w0,
                                                     const float* __restrict__ w1,
                                                     __hip_bfloat16* __restrict__ d0,
                                                     __hip_bfloat16* __restrict__ d1) {
  int i = blockIdx.x * 256 + threadIdx.x;  // 0 .. 1572863
  int l = i >= 786432;
  int i2 = i - (l ? 786432 : 0);
  const float* w = l ? w1 : w0;
  __hip_bfloat16* d = l ? d1 : d0;
  int fid = i2 >> 9;
  int within = i2 & 511;
  int lane = within >> 3;
  int j = within & 7;
  int mb = fid / 48;
  int kb = fid - mb * 48;
  int o = mb * 16 + (lane & 15);
  int r = kb * 32 + (lane >> 4) * 8 + j;
  int k = r >> 9, c = r & 511;
  d[i2] = __float2bfloat16(w[o * 1536 + c * 3 + k]);
}

// ---------- batched mask output: out[i] = (m != 0) ----------
__global__ __launch_bounds__(256) void mask_out_kernel(const float* __restrict__ m0,
                                                       const float* __restrict__ m1,
                                                       const float* __restrict__ m2,
                                                       float* __restrict__ o) {
  int i = blockIdx.x * 256 + threadIdx.x;  // 0 .. 28671
  float v;
  if (i < 16384) v = m0[i];
  else if (i < 24576) v = m1[i - 16384];
  else v = m2[i - 24576];
  o[i] = (v != 0.f) ? 1.f : 0.f;
}

// ---------- offset conv partials: P[g][(b*3+k)*T + t] = sum_{c in group g} ----------
// grid (B*(T>>6), 4); block = 4 waves x 64 t-lanes; wave covers 32 channels.
template <typename XT>
__global__ __launch_bounds__(256) void offconv_kernel(const XT* __restrict__ x,
                                                      const float* __restrict__ ow,
                                                      float* __restrict__ P, int T) {
  __shared__ float red[3][4][64];
  int tid = threadIdx.x;
  int lane = tid & 63, w = tid >> 6;
  int nchunk = T >> 6;
  int b = blockIdx.x / nchunk;
  int tb = (blockIdx.x % nchunk) << 6;
  int t = tb + lane;
  int c0 = blockIdx.y * 128 + w * 32;
  const XT* xb = x + ((size_t)b * 512 + c0) * T;
  float a0 = 0.f, a1 = 0.f, a2 = 0.f;
  for (int c = 0; c < 32; ++c) {
    const XT* xr = xb + (size_t)c * T;
    float xm = (t > 0) ? tf(xr[t - 1]) : 0.f;
    float x0 = tf(xr[t]);
    float xp = (t < T - 1) ? tf(xr[t + 1]) : 0.f;
    const float* wp = ow + (c0 + c) * 3;
    a0 += wp[0] * xm + wp[1] * x0 + wp[2] * xp;
    a1 += wp[1536] * xm + wp[1537] * x0 + wp[1538] * xp;
    a2 += wp[3072] * xm + wp[3073] * x0 + wp[3074] * xp;
  }
  red[0][w][lane] = a0;
  red[1][w][lane] = a1;
  red[2][w][lane] = a2;
  __syncthreads();
  if (w < 3) {  // wave w -> output tap k=w
    float s = red[w][0][lane] + red[w][1][lane] + red[w][2][lane] + red[w][3][lane];
    P[blockIdx.y * 24 * T + (b * 3 + w) * T + tb + lane] = s;
  }
}

// ---------- sampling, fragment-order (k-major), 4 kb per wave ----------
// off = offin + ob0 + sum(P1) [+ ob1 + sum(P2) for layer 2], computed inline.
template <typename XT, bool LAYER2>
__global__ __launch_bounds__(256) void sample_kernel(
    const XT* __restrict__ x, const float* __restrict__ offin,
    const float* __restrict__ P1, const float* __restrict__ P2,
    const float* __restrict__ ob0, const float* __restrict__ ob1,
    __hip_bfloat16* __restrict__ S, int T, int tsh) {
  int tid = threadIdx.x;
  int lane = tid & 63, wid = tid >> 6;
  int ntile = blockIdx.x * 4 + wid;
  int kb0 = blockIdx.y << 2;
  int n = (ntile << 4) + (lane & 15);
  int b = __builtin_amdgcn_readfirstlane(n >> tsh);  // wave-uniform (16-row tiles)
  int t = n & (T - 1);
  int ro = lane >> 4;
  int PT = 24 * T;

  int q0a[3];
  float fra[3];
#pragma unroll
  for (int k = 0; k < 3; ++k) {
    int oi = (b * 3 + k) * T + t;
    float o = offin[oi] + ob0[k];
#pragma unroll
    for (int g = 0; g < 4; ++g) o += P1[g * PT + oi];
    if (LAYER2) {
      o += ob1[k];
#pragma unroll
      for (int g = 0; g < 4; ++g) o += P2[g * PT + oi];
    }
    float pos = (float)(t + k - 1) + o;
    float p0f = floorf(pos);
    fra[k] = pos - p0f;
    q0a[k] = (int)p0f;
  }
  const XT* xb = x + ((size_t)b << (9 + tsh));
  short* Sp = (short*)S;

  for (int kb = kb0; kb < kb0 + 4; ++kb) {
    int r0 = kb * 32 + ro * 8;
    int k = r0 >> 9;           // constant across the octet (k-major)
    int c0 = r0 & 511;
    int q0 = (k == 0) ? q0a[0] : ((k == 1) ? q0a[1] : q0a[2]);
    float f = (k == 0) ? fra[0] : ((k == 1) ? fra[1] : fra[2]);
    bool ok0 = (unsigned)q0 < (unsigned)T;
    bool ok1 = (unsigned)(q0 + 1) < (unsigned)T;
    const XT* xr = xb + ((size_t)c0 << tsh);
    bf16x8 ov;
#pragma unroll
    for (int j = 0; j < 8; ++j) {
      float v0 = ok0 ? tf(xr[q0]) : 0.f;
      float v1 = ok1 ? tf(xr[q0 + 1]) : 0.f;
      __hip_bfloat16 hv = __float2bfloat16(v0 + (v1 - v0) * f);
      ov[j] = *reinterpret_cast<short*>(&hv);
      xr += ((size_t)1 << tsh);
    }
    *(bf16x8*)(Sp + (((size_t)(ntile * 48 + kb)) << 9) + lane * 8) = ov;
  }
}

// ---------- GEMM: 128m x 64n tile, BK=64, 4 waves (2m x 2n), fragment-packed operands.
template <bool OUT_BF16>
__global__ __launch_bounds__(256) void gemm_kernel(const __hip_bfloat16* __restrict__ Wf,
                                                   const __hip_bfloat16* __restrict__ Sf,
                                                   const float* __restrict__ bias,
                                                   const float* __restrict__ mask,
                                                   void* __restrict__ outp, int T, int tsh) {
  __shared__ short lds[12288];  // 16 W frags + 8 S frags, 1KB each
  int tid = threadIdx.x;
  int lane = tid & 63;
  int wid = tid >> 6;
  int lrow = lane & 15, lq = lane >> 4;
  int mq = wid & 1, nq = wid >> 1;
  int mbase = blockIdx.x << 3;  // 16-row units
  int nbase = blockIdx.y << 2;  // 16-col (ntile) units
  int m0 = blockIdx.x << 7;
  int n0 = blockIdx.y << 6;

  f32x4 acc[4][2] = {};

  const short* wg = (const short*)Wf + lane * 8;
  const short* sg = (const short*)Sf + lane * 8;

  for (int kt = 0; kt < 24; ++kt) {
    __syncthreads();
#pragma unroll
    for (int i = 0; i < 6; ++i) {
      int f = wid * 6 + i;  // 0..15: W frags (mt*2+kc); 16..23: S frags (nt*2+kc)
      const short* g;
      int fid;
      if (f < 16) {
        fid = (mbase + (f >> 1)) * 48 + (kt << 1) + (f & 1);
        g = wg;
      } else {
        int f2 = f - 16;
        fid = (nbase + (f2 >> 1)) * 48 + (kt << 1) + (f2 & 1);
        g = sg;
      }
      GLD_LDS16(g + ((size_t)fid << 9), &lds[f * 512]);
    }
    __syncthreads();
#pragma unroll
    for (int kc = 0; kc < 2; ++kc) {
      bf16x8 av[4], bv[2];
#pragma unroll
      for (int i = 0; i < 4; ++i)
        av[i] = *(const bf16x8*)&lds[((mq * 4 + i) * 2 + kc) * 512 + lane * 8];
#pragma unroll
      for (int j = 0; j < 2; ++j)
        bv[j] = *(const bf16x8*)&lds[8192 + ((nq * 2 + j) * 2 + kc) * 512 + lane * 8];
#pragma unroll
      for (int i = 0; i < 4; ++i)
#pragma unroll
        for (int j = 0; j < 2; ++j)
          acc[i][j] = __builtin_amdgcn_mfma_f32_16x16x32_bf16(av[i], bv[j], acc[i][j], 0, 0, 0);
    }
  }

  // epilogue: D row = (lane>>4)*4 + reg, col = lane&15
  int bb = n0 >> tsh;
  int tb = n0 & (T - 1);
  float bvals[4][4];
#pragma unroll
  for (int i = 0; i < 4; ++i)
#pragma unroll
    for (int r = 0; r < 4; ++r) bvals[i][r] = bias[m0 + mq * 64 + i * 16 + lq * 4 + r];
#pragma unroll
  for (int j = 0; j < 2; ++j) {
    int col = nq * 32 + j * 16 + lrow;
    int t = tb + col;
    float mk = mask[(bb << tsh) + t];
#pragma unroll
    for (int i = 0; i < 4; ++i) {
      int row = mq * 64 + i * 16 + lq * 4;
#pragma unroll
      for (int r = 0; r < 4; ++r) {
        float v = acc[i][j][r] + bvals[i][r];
        v = fmaxf(v, 0.f) * mk;
        size_t oi = ((((size_t)bb << 9) + (size_t)(m0 + row + r)) << tsh) + t;
        if (OUT_BF16)
          ((__hip_bfloat16*)outp)[oi] = __float2bfloat16(v);
        else
          ((float*)outp)[oi] = v;
      }
    }
  }
}

// ---------- launch ----------
extern "C" void kernel_launch(void* const* d_in, const int* in_sizes, int n_in, void* d_out,
                              int out_size, void* d_ws, size_t ws_size, hipStream_t stream) {
  const float* feats[3] = {(const float*)d_in[0], (const float*)d_in[3], (const float*)d_in[6]};
  const float* maskp[3] = {(const float*)d_in[1], (const float*)d_in[4], (const float*)d_in[7]};
  const float* offs[3] = {(const float*)d_in[2], (const float*)d_in[5], (const float*)d_in[8]};
  const float* w[2] = {(const float*)d_in[9], (const float*)d_in[13]};
  const float* bias[2] = {(const float*)d_in[10], (const float*)d_in[14]};
  const float* ow[2] = {(const float*)d_in[11], (const float*)d_in[15]};
  const float* ob[2] = {(const float*)d_in[12], (const float*)d_in[16]};

  const int Ts[3] = {2048, 1024, 512};
  const size_t YOFF[3] = {0, 8388608, 12582912};
  const size_t MOFF = 14680064;  // masks contiguous: 16384 + 8192 + 4096

  uint8_t* ws = (uint8_t*)d_ws;
  __hip_bfloat16* Wf[2] = {(__hip_bfloat16*)ws, (__hip_bfloat16*)(ws + 1572864)};
  float* P1 = (float*)(ws + 3145728);                     // 786,432 B (4 groups x 24T max)
  float* P2 = (float*)(ws + 3932160);                     // 786,432 B
  __hip_bfloat16* x1 = (__hip_bfloat16*)(ws + 4718592);   // 16,777,216 B
  __hip_bfloat16* Sm = (__hip_bfloat16*)(ws + 21495808);  // 50,331,648 B

  pack_w_kernel<<<1572864 / 256, 256, 0, stream>>>(w[0], w[1], Wf[0], Wf[1]);
  mask_out_kernel<<<28672 / 256, 256, 0, stream>>>(maskp[0], maskp[1], maskp[2],
                                                   (float*)d_out + MOFF);

  float* outf = (float*)d_out;
  for (int lv = 0; lv < 3; ++lv) {
    int T = Ts[lv];
    int tsh = 11 - lv;
    int N = 8 * T;

    // layer 1 (x = feats, fp32)
    offconv_kernel<float><<<dim3(8 * (T >> 6), 4), 256, 0, stream>>>(feats[lv], ow[0], P1, T);
    sample_kernel<float, false><<<dim3(N >> 6, 12), 256, 0, stream>>>(
        feats[lv], offs[lv], P1, P2, ob[0], ob[1], Sm, T, tsh);
    gemm_kernel<true><<<dim3(4, N >> 6), 256, 0, stream>>>(Wf[0], Sm, bias[0], maskp[lv],
                                                           (void*)x1, T, tsh);

    // layer 2 (x = x1, bf16)
    offconv_kernel<__hip_bfloat16><<<dim3(8 * (T >> 6), 4), 256, 0, stream>>>(x1, ow[1], P2, T);
    sample_kernel<__hip_bfloat16, true><<<dim3(N >> 6, 12), 256, 0, stream>>>(
        x1, offs[lv], P1, P2, ob[0], ob[1], Sm, T, tsh);
    gemm_kernel<false><<<dim3(4, N >> 6), 256, 0, stream>>>(Wf[1], Sm, bias[1], maskp[lv],
                                                            (void*)(outf + YOFF[lv]), T, tsh);
  }
}

// Round 5
// 537.878 us; speedup vs baseline: 2.3084x; 1.0560x over previous
//
#include <hip/hip_runtime.h>
#include <hip/hip_bf16.h>
#include <stdint.h>

// ---------- helpers ----------
__device__ __forceinline__ float tf(float v) { return v; }
__device__ __forceinline__ float tf(__hip_bfloat16 v) { return __bfloat162float(v); }

typedef __attribute__((ext_vector_type(8))) short bf16x8;
typedef __attribute__((ext_vector_type(4))) float f32x4;

// K-permutation: r = k*512 + c (k-major). W packed with the same map.
// W frag fid = mb*48 + kt: lane l holds o = mb*16+(l&15), elems r = kt*32+(l>>4)*8+j.

// ---------- setup: pack W0/W1 into fragment order + mask outputs ----------
__global__ __launch_bounds__(256) void setup_kernel(const float* __restrict__ w0,
                                                    const float* __restrict__ w1,
                                                    __hip_bfloat16* __restrict__ d0,
                                                    __hip_bfloat16* __restrict__ d1,
                                                    const float* __restrict__ m0,
                                                    const float* __restrict__ m1,
                                                    const float* __restrict__ m2,
                                                    float* __restrict__ mo) {
  int i = blockIdx.x * 256 + threadIdx.x;
  if (i < 1572864) {
    int l = i >= 786432;
    int i2 = i - (l ? 786432 : 0);
    const float* w = l ? w1 : w0;
    __hip_bfloat16* d = l ? d1 : d0;
    int fid = i2 >> 9, within = i2 & 511, lane = within >> 3, j = within & 7;
    int mb = fid / 48, kt = fid - mb * 48;
    int o = mb * 16 + (lane & 15);
    int r = kt * 32 + (lane >> 4) * 8 + j;
    int k = r >> 9, c = r & 511;
    d[i2] = __float2bfloat16(w[o * 1536 + c * 3 + k]);
  } else {
    int i2 = i - 1572864;
    if (i2 < 28672) {
      float v;
      if (i2 < 16384) v = m0[i2];
      else if (i2 < 24576) v = m1[i2 - 16384];
      else v = m2[i2 - 24576];
      mo[i2] = (v != 0.f) ? 1.f : 0.f;
    }
  }
}

// ---------- offset-conv partials, all levels batched ----------
// grid (448, 4): blockIdx.x ranges [0,256)=lv0, [256,384)=lv1, [384,448)=lv2.
// P per level at float offsets {0, 196608, 294912}; layout P[g*24T + (b*3+k)*T + t].
template <typename XT>
__global__ __launch_bounds__(256) void offconv_kernel(const XT* __restrict__ x0p,
                                                      const XT* __restrict__ x1p,
                                                      const XT* __restrict__ x2p,
                                                      const float* __restrict__ ow,
                                                      float* __restrict__ P) {
  __shared__ float red[3][4][64];
  int tid = threadIdx.x, lane = tid & 63, w = tid >> 6;
  int bx = blockIdx.x;
  int lv = (bx < 256) ? 0 : ((bx < 384) ? 1 : 2);
  int lbx = bx - ((lv == 0) ? 0 : ((lv == 1) ? 256 : 384));
  int tsh = 11 - lv;
  int T = 1 << tsh;
  const XT* x = (lv == 0) ? x0p : ((lv == 1) ? x1p : x2p);
  float* Pl = P + ((lv == 0) ? 0 : ((lv == 1) ? 196608 : 294912));
  int nchunk = T >> 6;
  int b = lbx >> (tsh - 6);
  int tb = (lbx & (nchunk - 1)) << 6;
  int t = tb + lane;
  int c0 = blockIdx.y * 128 + w * 32;
  const XT* xb = x + ((size_t)(b * 512 + c0) << tsh);
  float a0 = 0.f, a1 = 0.f, a2 = 0.f;
  for (int c = 0; c < 32; ++c) {
    const XT* xr = xb + ((size_t)c << tsh);
    float xm = (t > 0) ? tf(xr[t - 1]) : 0.f;
    float x0 = tf(xr[t]);
    float xp = (t < T - 1) ? tf(xr[t + 1]) : 0.f;
    const float* wp = ow + (c0 + c) * 3;
    a0 += wp[0] * xm + wp[1] * x0 + wp[2] * xp;
    a1 += wp[1536] * xm + wp[1537] * x0 + wp[1538] * xp;
    a2 += wp[3072] * xm + wp[3073] * x0 + wp[3074] * xp;
  }
  red[0][w][lane] = a0;
  red[1][w][lane] = a1;
  red[2][w][lane] = a2;
  __syncthreads();
  if (w < 3) {
    float s = red[w][0][lane] + red[w][1][lane] + red[w][2][lane] + red[w][3][lane];
    Pl[blockIdx.y * (24 << tsh) + ((b * 3 + w) << tsh) + tb + lane] = s;
  }
}

// ---------- fused deform-GEMM, all levels batched ----------
// grid (448, 2): x = n-strip (64 t of one b, level-batched), y = m-half (256 rows).
// Block 256 thr = 4 waves (m-split 4: wave = 64m x 64n). BK=32, 16x16x32 MFMA.
// S-fragments generated in-kernel into a 2x4KB LDS double buffer (1 barrier/kt);
// W A-fragments loaded global->VGPR (packed 1KB frags, L2-hot).
template <typename XT, bool LAYER2, bool OUT_BF16>
__global__ __launch_bounds__(256, 3) void dgemm_kernel(
    const XT* __restrict__ x0p, const XT* __restrict__ x1p, const XT* __restrict__ x2p,
    const __hip_bfloat16* __restrict__ Wf,
    const float* __restrict__ off0, const float* __restrict__ off1p,
    const float* __restrict__ off2p,
    const float* __restrict__ P1, const float* __restrict__ P2,
    const float* __restrict__ ob0v, const float* __restrict__ ob1v,
    const float* __restrict__ bias,
    const float* __restrict__ mk0, const float* __restrict__ mk1, const float* __restrict__ mk2,
    void* __restrict__ o0, void* __restrict__ o1, void* __restrict__ o2) {
  __shared__ short sS[2][2048];  // dbuf: 4 frags x 512 elems
  __shared__ float s_f[3][64];
  __shared__ int s_q0[3][64];
  int tid = threadIdx.x, lane = tid & 63, wid = tid >> 6;
  int bx = blockIdx.x;
  int lv = (bx < 256) ? 0 : ((bx < 384) ? 1 : 2);
  int lbx = bx - ((lv == 0) ? 0 : ((lv == 1) ? 256 : 384));
  int tsh = 11 - lv;
  int T = 1 << tsh;
  const XT* x = (lv == 0) ? x0p : ((lv == 1) ? x1p : x2p);
  const float* offin = (lv == 0) ? off0 : ((lv == 1) ? off1p : off2p);
  const float* mask = (lv == 0) ? mk0 : ((lv == 1) ? mk1 : mk2);
  void* outp = (lv == 0) ? o0 : ((lv == 1) ? o1 : o2);
  int Pofs = (lv == 0) ? 0 : ((lv == 1) ? 196608 : 294912);
  const float* P1l = P1 + Pofs;
  const float* P2l = P2 + Pofs;
  int nchunk = T >> 6;
  int b = lbx >> (tsh - 6);
  int tb = (lbx & (nchunk - 1)) << 6;
  int mhalf = blockIdx.y;

  // --- per-block offset table: q0,f for 3 taps x 64 t ---
  if (tid < 192) {
    int k = tid >> 6, tl = tid & 63, t = tb + tl;
    int oi = ((b * 3 + k) << tsh) + t;
    int PT = 24 << tsh;
    float o = offin[oi] + ob0v[k];
    o += P1l[oi] + P1l[PT + oi] + P1l[2 * PT + oi] + P1l[3 * PT + oi];
    if (LAYER2) {
      o += ob1v[k];
      o += P2l[oi] + P2l[PT + oi] + P2l[2 * PT + oi] + P2l[3 * PT + oi];
    }
    float pos = (float)(t + k - 1) + o;
    float pf = floorf(pos);
    s_f[k][tl] = pos - pf;
    s_q0[k][tl] = (int)pf;
  }
  __syncthreads();

  f32x4 acc[4][4] = {};
  // generator role: thread -> frag nt = wid, lane gl: n = nt*16+(gl&15), octet gl>>4
  int gl = lane;
  int gtl = (wid << 4) + (gl & 15);  // t_local of generated element
  const XT* xrowbase = x + ((size_t)b << (9 + tsh));
  const short* wfp = (const short*)Wf + (size_t)(mhalf * 16 + wid * 4) * 48 * 512 + lane * 8;

  int buf = 0;
  for (int k3 = 0; k3 < 3; ++k3) {
    int q0 = s_q0[k3][gtl];
    float f = s_f[k3][gtl];
    bool ok0 = (unsigned)q0 < (unsigned)T;
    bool ok1 = (unsigned)(q0 + 1) < (unsigned)T;
#pragma unroll 4
    for (int kk = 0; kk < 16; ++kk) {
      int kt = k3 * 16 + kk;
      int c0 = kk * 32 + (gl >> 4) * 8;
      const XT* xr = xrowbase + ((size_t)c0 << tsh);
      bf16x8 ov;
#pragma unroll
      for (int j = 0; j < 8; ++j) {
        float v0 = ok0 ? tf(xr[q0]) : 0.f;
        float v1 = ok1 ? tf(xr[q0 + 1]) : 0.f;
        __hip_bfloat16 hv = __float2bfloat16(v0 + (v1 - v0) * f);
        ov[j] = *reinterpret_cast<short*>(&hv);
        xr += ((size_t)1 << tsh);
      }
      *(bf16x8*)&sS[buf][(wid << 9) + gl * 8] = ov;
      __syncthreads();
      bf16x8 av[4], bv[4];
#pragma unroll
      for (int i = 0; i < 4; ++i)
        av[i] = *(const bf16x8*)(wfp + ((size_t)(i * 48 + kt) << 9));
#pragma unroll
      for (int j = 0; j < 4; ++j) bv[j] = *(const bf16x8*)&sS[buf][(j << 9) + lane * 8];
#pragma unroll
      for (int i = 0; i < 4; ++i)
#pragma unroll
        for (int j = 0; j < 4; ++j)
          acc[i][j] = __builtin_amdgcn_mfma_f32_16x16x32_bf16(av[i], bv[j], acc[i][j], 0, 0, 0);
      buf ^= 1;
    }
  }

  // --- epilogue: D row = (lane>>4)*4 + reg, col = lane&15 ---
  int lrow = lane & 15, lq = lane >> 4;
  int mbase = mhalf * 256 + wid * 64;
  float bvals[4][4];
#pragma unroll
  for (int i = 0; i < 4; ++i)
#pragma unroll
    for (int r = 0; r < 4; ++r) bvals[i][r] = bias[mbase + i * 16 + lq * 4 + r];
#pragma unroll
  for (int j = 0; j < 4; ++j) {
    int col = j * 16 + lrow;
    float mk = mask[(b << tsh) + tb + col];
#pragma unroll
    for (int i = 0; i < 4; ++i) {
      int m = mbase + i * 16 + lq * 4;
#pragma unroll
      for (int r = 0; r < 4; ++r) {
        float v = acc[i][j][r] + bvals[i][r];
        v = fmaxf(v, 0.f) * mk;
        size_t oi = (((size_t)(b * 512 + m + r)) << tsh) + tb + col;
        if (OUT_BF16)
          ((__hip_bfloat16*)outp)[oi] = __float2bfloat16(v);
        else
          ((float*)outp)[oi] = v;
      }
    }
  }
}

// ---------- launch ----------
extern "C" void kernel_launch(void* const* d_in, const int* in_sizes, int n_in, void* d_out,
                              int out_size, void* d_ws, size_t ws_size, hipStream_t stream) {
  const float* feats[3] = {(const float*)d_in[0], (const float*)d_in[3], (const float*)d_in[6]};
  const float* maskp[3] = {(const float*)d_in[1], (const float*)d_in[4], (const float*)d_in[7]};
  const float* offs[3] = {(const float*)d_in[2], (const float*)d_in[5], (const float*)d_in[8]};
  const float* w[2] = {(const float*)d_in[9], (const float*)d_in[13]};
  const float* bias[2] = {(const float*)d_in[10], (const float*)d_in[14]};
  const float* ow[2] = {(const float*)d_in[11], (const float*)d_in[15]};
  const float* ob[2] = {(const float*)d_in[12], (const float*)d_in[16]};

  const size_t YOFF[3] = {0, 8388608, 12582912};
  const size_t MOFF = 14680064;

  uint8_t* ws = (uint8_t*)d_ws;
  __hip_bfloat16* Wf0 = (__hip_bfloat16*)ws;
  __hip_bfloat16* Wf1 = (__hip_bfloat16*)(ws + 1572864);
  float* P1 = (float*)(ws + 3145728);                    // 1,376,256 B
  float* P2 = (float*)(ws + 4521984);                    // 1,376,256 B
  __hip_bfloat16* x1 = (__hip_bfloat16*)(ws + 5898240);  // 29,360,128 B

  __hip_bfloat16* x1p[3] = {x1, x1 + YOFF[1], x1 + YOFF[2]};
  float* outf = (float*)d_out;

  setup_kernel<<<6256, 256, 0, stream>>>(w[0], w[1], Wf0, Wf1, maskp[0], maskp[1], maskp[2],
                                         outf + MOFF);

  // layer 1
  offconv_kernel<float><<<dim3(448, 4), 256, 0, stream>>>(feats[0], feats[1], feats[2], ow[0], P1);
  dgemm_kernel<float, false, true><<<dim3(448, 2), 256, 0, stream>>>(
      feats[0], feats[1], feats[2], Wf0, offs[0], offs[1], offs[2], P1, P1, ob[0], ob[1], bias[0],
      maskp[0], maskp[1], maskp[2], (void*)x1p[0], (void*)x1p[1], (void*)x1p[2]);

  // layer 2
  offconv_kernel<__hip_bfloat16><<<dim3(448, 4), 256, 0, stream>>>(x1p[0], x1p[1], x1p[2], ow[1],
                                                                   P2);
  dgemm_kernel<__hip_bfloat16, true, false><<<dim3(448, 2), 256, 0, stream>>>(
      x1p[0], x1p[1], x1p[2], Wf1, offs[0], offs[1], offs[2], P1, P2, ob[0], ob[1], bias[1],
      maskp[0], maskp[1], maskp[2], (void*)(outf + YOFF[0]), (void*)(outf + YOFF[1]),
      (void*)(outf + YOFF[2]));
}

// Round 7
// 352.791 us; speedup vs baseline: 3.5194x; 1.5246x over previous
//
#include <hip/hip_runtime.h>
#include <hip/hip_bf16.h>
#include <stdint.h>

typedef __attribute__((ext_vector_type(8))) short bf16x8;
typedef __attribute__((ext_vector_type(4))) short bf16x4;
typedef __attribute__((ext_vector_type(4))) float f32x4;

__device__ __forceinline__ float b2f(short s) {
  union { unsigned u; float f; } cv;
  cv.u = ((unsigned)(unsigned short)s) << 16;
  return cv.f;
}
__device__ __forceinline__ short f2b(float f) {
  __hip_bfloat16 h = __float2bfloat16(f);
  return *reinterpret_cast<short*>(&h);
}

// Layouts:
//  xT[b][t][c] bf16 (c contiguous, 512/row), per-level elem offsets {0, 8388608, 12582912}.
//  W frags (k-major r = k*512+c): fid = mb*48+kt, lane l: o = mb*16+(l&15), r = kt*32+(l>>4)*8+j.
//  owF1 frags (j-major rr = j*512+c): fid = kt (0..47), lane l: k = l&15 (rows>=3 zero),
//    rr = kt*32+(l>>4)*8+j; stored twice: hi = bf16(v), lo = bf16(v - hi).

// ---------- setup: pack W0/W1 frags, owF1 hi/lo frags, mask outputs ----------
__global__ __launch_bounds__(256) void setup_kernel(
    const float* __restrict__ w0, const float* __restrict__ w1,
    __hip_bfloat16* __restrict__ d0, __hip_bfloat16* __restrict__ d1,
    const float* __restrict__ ow1,
    __hip_bfloat16* __restrict__ of1hi, __hip_bfloat16* __restrict__ of1lo,
    const float* __restrict__ m0, const float* __restrict__ m1, const float* __restrict__ m2,
    float* __restrict__ mo) {
  int i = blockIdx.x * 256 + threadIdx.x;
  if (i < 1572864) {
    int l = i >= 786432;
    int i2 = i - (l ? 786432 : 0);
    const float* w = l ? w1 : w0;
    __hip_bfloat16* d = l ? d1 : d0;
    int fid = i2 >> 9, within = i2 & 511, lane = within >> 3, j = within & 7;
    int mb = fid / 48, kt = fid - mb * 48;
    int o = mb * 16 + (lane & 15);
    int r = kt * 32 + (lane >> 4) * 8 + j;
    int k = r >> 9, c = r & 511;
    d[i2] = __float2bfloat16(w[o * 1536 + c * 3 + k]);
  } else if (i < 1597440) {  // 1572864 + 24576 : owF1 hi+lo (one pass per elem)
    int i4 = i - 1572864;
    int fid = i4 >> 9, within = i4 & 511, lane = within >> 3, jj = within & 7;
    int o = lane & 15;
    int rr = fid * 32 + (lane >> 4) * 8 + jj;  // 0..1535
    int j = rr >> 9, c = rr & 511;
    float v = (o < 3) ? ow1[o * 1536 + c * 3 + j] : 0.f;
    __hip_bfloat16 hi = __float2bfloat16(v);
    of1hi[i4] = hi;
    of1lo[i4] = __float2bfloat16(v - __bfloat162float(hi));
  } else {
    int i2 = i - 1597440;
    if (i2 < 28672) {
      float v;
      if (i2 < 16384) v = m0[i2];
      else if (i2 < 24576) v = m1[i2 - 16384];
      else v = m2[i2 - 24576];
      mo[i2] = (v != 0.f) ? 1.f : 0.f;
    }
  }
}

// ---------- transpose feats (b,c,t) fp32 -> (b,t,c) bf16, 3 levels batched ----------
__global__ __launch_bounds__(256) void transpose_kernel(const float* __restrict__ x0,
                                                        const float* __restrict__ x1,
                                                        const float* __restrict__ x2,
                                                        __hip_bfloat16* __restrict__ xT) {
  __shared__ float fl[64][65];
  int f = blockIdx.x;
  int lv = (f < 2048) ? 0 : ((f < 3072) ? 1 : 2);
  int f2 = f - ((lv == 0) ? 0 : ((lv == 1) ? 2048 : 3072));
  int tsh = 11 - lv;
  const float* x = (lv == 0) ? x0 : ((lv == 1) ? x1 : x2);
  __hip_bfloat16* xo = xT + ((lv == 0) ? 0 : ((lv == 1) ? 8388608 : 12582912));
  int perb = (1 << (tsh - 6)) * 8;
  int b = f2 / perb;
  int rem = f2 - b * perb;
  int t0 = (rem >> 3) << 6;
  int c0 = (rem & 7) << 6;
  int tid = threadIdx.x;
  int tl = tid & 63, cw = tid >> 6;
  const float* xb = x + ((size_t)(b * 512 + c0) << tsh) + t0;
#pragma unroll
  for (int i = 0; i < 16; ++i) {
    int cl = cw + i * 4;
    fl[cl][tl] = xb[((size_t)cl << tsh) + tl];
  }
  __syncthreads();
  int tl2 = tid >> 2;
  int cb = (tid & 3) << 4;
  short* orow = (short*)xo + (((size_t)(b << tsh) + t0 + tl2) << 9) + c0 + cb;
#pragma unroll
  for (int h = 0; h < 2; ++h) {
    bf16x8 v;
#pragma unroll
    for (int j = 0; j < 8; ++j) v[j] = f2b(fl[cb + h * 8 + j][tl2]);
    *(bf16x8*)(orow + h * 8) = v;
  }
}

// ---------- layer-1 offset-conv partials, fp32 VALU, levels batched ----------
// grid (448, 4): bx [0,256)=lv0, [256,384)=lv1, [384,448)=lv2.
// P level float offsets {0, 196608, 294912}; layout P[g*(24<<tsh) + ((b*3+k)<<tsh) + t].
__global__ __launch_bounds__(256) void offconv1_kernel(const float* __restrict__ x0p,
                                                       const float* __restrict__ x1p,
                                                       const float* __restrict__ x2p,
                                                       const float* __restrict__ ow,
                                                       float* __restrict__ P) {
  __shared__ float red[3][4][64];
  int tid = threadIdx.x, lane = tid & 63, w = tid >> 6;
  int bx = blockIdx.x;
  int lv = (bx < 256) ? 0 : ((bx < 384) ? 1 : 2);
  int lbx = bx - ((lv == 0) ? 0 : ((lv == 1) ? 256 : 384));
  int tsh = 11 - lv;
  int T = 1 << tsh;
  const float* x = (lv == 0) ? x0p : ((lv == 1) ? x1p : x2p);
  float* Pl = P + ((lv == 0) ? 0 : ((lv == 1) ? 196608 : 294912));
  int nchunk = T >> 6;
  int b = lbx >> (tsh - 6);
  int tb = (lbx & (nchunk - 1)) << 6;
  int t = tb + lane;
  int c0 = blockIdx.y * 128 + w * 32;
  const float* xb = x + ((size_t)(b * 512 + c0) << tsh);
  float a0 = 0.f, a1 = 0.f, a2 = 0.f;
  for (int c = 0; c < 32; ++c) {
    const float* xr = xb + ((size_t)c << tsh);
    float xm = (t > 0) ? xr[t - 1] : 0.f;
    float x0 = xr[t];
    float xp = (t < T - 1) ? xr[t + 1] : 0.f;
    const float* wp = ow + (c0 + c) * 3;
    a0 += wp[0] * xm + wp[1] * x0 + wp[2] * xp;
    a1 += wp[1536] * xm + wp[1537] * x0 + wp[1538] * xp;
    a2 += wp[3072] * xm + wp[3073] * x0 + wp[3074] * xp;
  }
  red[0][w][lane] = a0;
  red[1][w][lane] = a1;
  red[2][w][lane] = a2;
  __syncthreads();
  if (w < 3) {
    float s = red[w][0][lane] + red[w][1][lane] + red[w][2][lane] + red[w][3][lane];
    Pl[blockIdx.y * (24 << tsh) + ((b * 3 + w) << tsh) + tb + lane] = s;
  }
}

// ---------- layer-2 offset conv: skinny MFMA on x1T, ow in hi/lo bf16 ----------
// One wave per 16-n tile (1792 total); writes conv sum to offc2.
__global__ __launch_bounds__(256, 4) void offconv2_kernel(const __hip_bfloat16* __restrict__ xT,
                                                          const __hip_bfloat16* __restrict__ oHi,
                                                          const __hip_bfloat16* __restrict__ oLo,
                                                          float* __restrict__ offc) {
  int tid = threadIdx.x, lane = tid & 63, wid = tid >> 6;
  int nt = blockIdx.x * 4 + wid;
  int lv = (nt < 1024) ? 0 : ((nt < 1536) ? 1 : 2);
  int ntl = nt - ((lv == 0) ? 0 : ((lv == 1) ? 1024 : 1536));
  int tsh = 11 - lv;
  int T = 1 << tsh;
  const short* xp = (const short*)xT + ((lv == 0) ? 0 : ((lv == 1) ? 8388608 : 12582912));
  float* oc = offc + ((lv == 0) ? 0 : ((lv == 1) ? 49152 : 73728));
  int n = (ntl << 4) + (lane & 15);
  int b = n >> tsh;
  int t = n & (T - 1);
  const short* hip_ = (const short*)oHi + lane * 8;
  const short* lop_ = (const short*)oLo + lane * 8;
  int co = (lane >> 4) << 3;
  f32x4 acc = {};
  for (int kt = 0; kt < 48; ++kt) {
    int j = kt >> 4;
    int c0 = ((kt & 15) << 5) + co;
    int row = t + j - 1;
    bf16x8 bv = {};
    if ((unsigned)row < (unsigned)T)
      bv = *(const bf16x8*)(xp + (((size_t)(b << tsh) + row) << 9) + c0);
    bf16x8 ah = *(const bf16x8*)(hip_ + ((size_t)kt << 9));
    bf16x8 al = *(const bf16x8*)(lop_ + ((size_t)kt << 9));
    acc = __builtin_amdgcn_mfma_f32_16x16x32_bf16(ah, bv, acc, 0, 0, 0);
    acc = __builtin_amdgcn_mfma_f32_16x16x32_bf16(al, bv, acc, 0, 0, 0);
  }
  if ((lane >> 4) == 0) {
#pragma unroll
    for (int r = 0; r < 3; ++r) oc[((b * 3 + r) << tsh) + t] = acc[r];
  }
}

// ---------- fused deform-GEMM from transposed x ----------
// grid (448, 2): x = 64-t strip (level-batched), y = m-half (256 rows). 4 waves m-split.
// BK=32; S-frags generated from 2 contiguous bf16x8 row loads + lerp into 2x4KB LDS dbuf.
template <bool LAYER2, bool OUT_BF16>
__global__ __launch_bounds__(256, 3) void dgemm_kernel(
    const __hip_bfloat16* __restrict__ xT, const __hip_bfloat16* __restrict__ Wf,
    const float* __restrict__ off0, const float* __restrict__ off1,
    const float* __restrict__ off2, const float* __restrict__ P1,
    const float* __restrict__ offc2, const float* __restrict__ ob0v,
    const float* __restrict__ ob1v, const float* __restrict__ bias,
    const float* __restrict__ mk0, const float* __restrict__ mk1, const float* __restrict__ mk2,
    void* __restrict__ o0, void* __restrict__ o1, void* __restrict__ o2) {
  __shared__ short sS[2][2048];
  __shared__ float s_f[3][64];
  __shared__ int s_q0[3][64];
  int tid = threadIdx.x, lane = tid & 63, wid = tid >> 6;
  int bx = blockIdx.x;
  int lv = (bx < 256) ? 0 : ((bx < 384) ? 1 : 2);
  int lbx = bx - ((lv == 0) ? 0 : ((lv == 1) ? 256 : 384));
  int tsh = 11 - lv;
  int T = 1 << tsh;
  const short* xp = (const short*)xT + ((lv == 0) ? 0 : ((lv == 1) ? 8388608 : 12582912));
  const float* offin = (lv == 0) ? off0 : ((lv == 1) ? off1 : off2);
  const float* P1l = P1 + ((lv == 0) ? 0 : ((lv == 1) ? 196608 : 294912));
  const float* oc2 = offc2 + ((lv == 0) ? 0 : ((lv == 1) ? 49152 : 73728));
  const float* mask = (lv == 0) ? mk0 : ((lv == 1) ? mk1 : mk2);
  void* outp = (lv == 0) ? o0 : ((lv == 1) ? o1 : o2);
  int nchunk = T >> 6;
  int b = lbx >> (tsh - 6);
  int tb = (lbx & (nchunk - 1)) << 6;
  int mhalf = blockIdx.y;

  if (tid < 192) {
    int k = tid >> 6, tl = tid & 63, t = tb + tl;
    int oi = ((b * 3 + k) << tsh) + t;
    int PT = 24 << tsh;
    float o = offin[oi] + ob0v[k];
    o += P1l[oi] + P1l[PT + oi] + P1l[2 * PT + oi] + P1l[3 * PT + oi];
    if (LAYER2) o += ob1v[k] + oc2[oi];
    float pos = (float)(t + k - 1) + o;
    float pf = floorf(pos);
    s_f[k][tl] = pos - pf;
    s_q0[k][tl] = (int)pf;
  }
  __syncthreads();

  f32x4 acc[4][4] = {};
  int gtl = (wid << 4) + (lane & 15);
  const short* wfp = (const short*)Wf + (size_t)(mhalf * 16 + wid * 4) * 48 * 512 + lane * 8;
  int buf = 0;
  for (int k3 = 0; k3 < 3; ++k3) {
    int q0 = s_q0[k3][gtl];
    float f = s_f[k3][gtl];
    bool ok0 = (unsigned)q0 < (unsigned)T;
    bool ok1 = (unsigned)(q0 + 1) < (unsigned)T;
    const short* r0p = xp + (((size_t)(b << tsh) + q0) << 9) + ((lane >> 4) << 3);
#pragma unroll 4
    for (int kk = 0; kk < 16; ++kk) {
      int kt = k3 * 16 + kk;
      bf16x8 v0 = {}, v1 = {};
      if (ok0) v0 = *(const bf16x8*)(r0p + (kk << 5));
      if (ok1) v1 = *(const bf16x8*)(r0p + 512 + (kk << 5));
      bf16x8 ov;
#pragma unroll
      for (int j = 0; j < 8; ++j) {
        float a = b2f(v0[j]);
        ov[j] = f2b(a + (b2f(v1[j]) - a) * f);
      }
      *(bf16x8*)&sS[buf][(wid << 9) + lane * 8] = ov;
      __syncthreads();
      bf16x8 av[4], bv[4];
#pragma unroll
      for (int i = 0; i < 4; ++i)
        av[i] = *(const bf16x8*)(wfp + ((size_t)(i * 48 + kt) << 9));
#pragma unroll
      for (int jj = 0; jj < 4; ++jj) bv[jj] = *(const bf16x8*)&sS[buf][(jj << 9) + lane * 8];
#pragma unroll
      for (int i = 0; i < 4; ++i)
#pragma unroll
        for (int jj = 0; jj < 4; ++jj)
          acc[i][jj] = __builtin_amdgcn_mfma_f32_16x16x32_bf16(av[i], bv[jj], acc[i][jj], 0, 0, 0);
      buf ^= 1;
    }
  }

  // epilogue: D row = (lane>>4)*4 + reg (m), col = lane&15 (t)
  int lrow = lane & 15, lq = lane >> 4;
  int mbase = mhalf * 256 + wid * 64;
  float bvals[4][4];
#pragma unroll
  for (int i = 0; i < 4; ++i)
#pragma unroll
    for (int r = 0; r < 4; ++r) bvals[i][r] = bias[mbase + i * 16 + lq * 4 + r];
#pragma unroll
  for (int j = 0; j < 4; ++j) {
    int col = j * 16 + lrow;
    int t = tb + col;
    float mk = mask[(b << tsh) + t];
    if (OUT_BF16) {
      short* orow = (short*)outp + (((size_t)(b << tsh) + t) << 9);
#pragma unroll
      for (int i = 0; i < 4; ++i) {
        bf16x4 pv;
#pragma unroll
        for (int r = 0; r < 4; ++r)
          pv[r] = f2b(fmaxf(acc[i][j][r] + bvals[i][r], 0.f) * mk);
        *(bf16x4*)(orow + mbase + i * 16 + lq * 4) = pv;
      }
    } else {
#pragma unroll
      for (int i = 0; i < 4; ++i) {
        int m = mbase + i * 16 + lq * 4;
#pragma unroll
        for (int r = 0; r < 4; ++r) {
          float v = fmaxf(acc[i][j][r] + bvals[i][r], 0.f) * mk;
          ((float*)outp)[(((size_t)(b * 512 + m + r)) << tsh) + t] = v;
        }
      }
    }
  }
}

// ---------- launch ----------
extern "C" void kernel_launch(void* const* d_in, const int* in_sizes, int n_in, void* d_out,
                              int out_size, void* d_ws, size_t ws_size, hipStream_t stream) {
  const float* feats[3] = {(const float*)d_in[0], (const float*)d_in[3], (const float*)d_in[6]};
  const float* maskp[3] = {(const float*)d_in[1], (const float*)d_in[4], (const float*)d_in[7]};
  const float* offs[3] = {(const float*)d_in[2], (const float*)d_in[5], (const float*)d_in[8]};
  const float* w[2] = {(const float*)d_in[9], (const float*)d_in[13]};
  const float* bias[2] = {(const float*)d_in[10], (const float*)d_in[14]};
  const float* ow[2] = {(const float*)d_in[11], (const float*)d_in[15]};
  const float* ob[2] = {(const float*)d_in[12], (const float*)d_in[16]};

  const size_t YOFF[3] = {0, 8388608, 12582912};
  const size_t MOFF = 14680064;

  uint8_t* ws = (uint8_t*)d_ws;
  __hip_bfloat16* Wf0 = (__hip_bfloat16*)ws;                 // 1,572,864 B
  __hip_bfloat16* Wf1 = (__hip_bfloat16*)(ws + 1572864);     // 1,572,864 B
  __hip_bfloat16* owF1hi = (__hip_bfloat16*)(ws + 3145728);  // 49,152 B
  __hip_bfloat16* owF1lo = (__hip_bfloat16*)(ws + 3194880);  // 49,152 B
  float* P1 = (float*)(ws + 3244032);                        // 1,376,256 B
  float* offc2 = (float*)(ws + 4620288);                     // 344,064 B
  __hip_bfloat16* fT = (__hip_bfloat16*)(ws + 8388608);      // 29,360,128 B
  __hip_bfloat16* x1T = (__hip_bfloat16*)(ws + 37748736);    // 29,360,128 B (end 67,108,864)

  float* outf = (float*)d_out;

  setup_kernel<<<6448, 256, 0, stream>>>(w[0], w[1], Wf0, Wf1, ow[1], owF1hi, owF1lo,
                                         maskp[0], maskp[1], maskp[2], outf + MOFF);
  transpose_kernel<<<3584, 256, 0, stream>>>(feats[0], feats[1], feats[2], fT);
  offconv1_kernel<<<dim3(448, 4), 256, 0, stream>>>(feats[0], feats[1], feats[2], ow[0], P1);

  // layer 1
  dgemm_kernel<false, true><<<dim3(448, 2), 256, 0, stream>>>(
      fT, Wf0, offs[0], offs[1], offs[2], P1, offc2, ob[0], ob[1], bias[0],
      maskp[0], maskp[1], maskp[2], (void*)x1T, (void*)(x1T + YOFF[1]), (void*)(x1T + YOFF[2]));

  // layer 2
  offconv2_kernel<<<448, 256, 0, stream>>>(x1T, owF1hi, owF1lo, offc2);
  dgemm_kernel<true, false><<<dim3(448, 2), 256, 0, stream>>>(
      x1T, Wf1, offs[0], offs[1], offs[2], P1, offc2, ob[0], ob[1], bias[1],
      maskp[0], maskp[1], maskp[2], (void*)(outf + YOFF[0]), (void*)(outf + YOFF[1]),
      (void*)(outf + YOFF[2]));
}